// Round 5
// baseline (12554.008 us; speedup 1.0000x reference)
//
#include <hip/hip_runtime.h>
#include <hip/hip_bf16.h>

#define DMODEL 640
#define HDIM   1760
#define G4     7040      // 4*H
#define VOCAB  50257
#define VPAD   50304     // 393*128
#define SEQ    512
#define MROWS  4096      // B*S
#define NWG    220       // scan workgroups (220*8 = 1760 j's)
#define WSTRIDE 1800     // Ws row stride in shorts (3600B -> 2-way bank alias = free)
#define POIS   0x7FC07FC0u   // two bf16 NaNs; h = og*tanh(c) in (-1,1) can never encode this

typedef __attribute__((ext_vector_type(8))) short short8_t;
typedef __attribute__((ext_vector_type(4))) short s16x4;
typedef __attribute__((ext_vector_type(4))) float f32x4;

static __device__ __forceinline__ float bf2f(short s) {
  union { unsigned int u; float f; } v;
  v.u = ((unsigned int)(unsigned short)s) << 16;
  return v.f;
}
static __device__ __forceinline__ short f2bf(float f) {
  union { float f; unsigned int u; } v; v.f = f;
  unsigned int r = v.u + 0x7fffu + ((v.u >> 16) & 1u);  // RNE, non-NaN inputs
  return (short)(r >> 16);
}
// fast sigmoid / tanh (v_exp + v_rcp; exact saturation at +-inf)
static __device__ __forceinline__ float fsig(float x) {
  return __builtin_amdgcn_rcpf(1.f + __expf(-x));
}
static __device__ __forceinline__ float ftanh(float x) {
  return 1.f - 2.f * __builtin_amdgcn_rcpf(1.f + __expf(2.f * x));
}

// coherent (bypass L1/L2) ops for cross-XCD h exchange
static __device__ __forceinline__ uint4 ld16_coh(const short* p) {
  uint4 r;
  asm volatile("global_load_dwordx4 %0, %1, off sc0 sc1" : "=v"(r) : "v"(p));
  return r;
}
static __device__ __forceinline__ void st8_coh(short* p, s16x4 v) {
  asm volatile("global_store_dwordx2 %0, %1, off sc0 sc1" :: "v"(p), "v"(v) : "memory");
}

// ---------------- poison fill (data-as-flag init) ----------------
__global__ void fill_poison(unsigned int* __restrict__ dst, long n4) {
  long i = (long)blockIdx.x * blockDim.x + threadIdx.x;
  if (i < n4) {
    uint4 v = {POIS, POIS, POIS, POIS};
    *(uint4*)(dst + i * 4) = v;
  }
}

// ---------------- f32 -> bf16 conversion ----------------
__global__ void cvt_f32_bf16(const float* __restrict__ src, short* __restrict__ dst, long n) {
  long i = ((long)blockIdx.x * blockDim.x + threadIdx.x) * 8;
  if (i + 8 <= n) {
    float4 a = *(const float4*)(src + i);
    float4 b = *(const float4*)(src + i + 4);
    short8_t o;
    o[0] = f2bf(a.x); o[1] = f2bf(a.y); o[2] = f2bf(a.z); o[3] = f2bf(a.w);
    o[4] = f2bf(b.x); o[5] = f2bf(b.y); o[6] = f2bf(b.z); o[7] = f2bf(b.w);
    *(short8_t*)(dst + i) = o;
  } else {
    for (; i < n; ++i) dst[i] = f2bf(src[i]);
  }
}

// ---------------- embedding gather ----------------
__global__ void embed_gather(const int* __restrict__ ids, const float* __restrict__ emb,
                             short* __restrict__ x0) {
  int row = blockIdx.x;            // b*512+s
  int id  = ids[row];
  const float* s = emb + (long)id * DMODEL;
  short* d = x0 + (long)row * DMODEL;
  for (int c = threadIdx.x; c < DMODEL; c += blockDim.x) d[c] = f2bf(s[c]);
}

// ---------------- bf16 MFMA GEMM: C[M,N] = A[M,K] * B[N,K]^T ----------------
#define GLDS16(gp, lp) __builtin_amdgcn_global_load_lds( \
    (const __attribute__((address_space(1))) unsigned int*)(gp), \
    (__attribute__((address_space(3))) unsigned int*)(lp), 16, 0, 0)

template<int OUT_BF16>
__global__ __launch_bounds__(256, 2) void gemm_btn(
    const short* __restrict__ A, const short* __restrict__ B, void* __restrict__ C,
    int M, int N, int K)
{
  __shared__ short As[128 * 32];
  __shared__ short Bs[128 * 32];
  const int bn = blockIdx.x * 128, bm = blockIdx.y * 128;
  const int tid = threadIdx.x, lane = tid & 63, wid = tid >> 6;
  const int wm = (wid >> 1) * 64, wn = (wid & 1) * 64;

  f32x4 acc[4][4] = {};

  const int c0 = 2 * wid;
  const int srow = c0 * 16 + (lane >> 2);
  const int scol = (lane & 3) * 8;
  const long aoff0 = (long)(bm + srow) * K + scol;
  const long aoff1 = aoff0 + 16 * (long)K;
  const long boff0 = (long)(bn + srow) * K + scol;
  const long boff1 = boff0 + 16 * (long)K;
  short* Asw0 = As + c0 * 512; short* Asw1 = Asw0 + 512;
  short* Bsw0 = Bs + c0 * 512; short* Bsw1 = Bsw0 + 512;

  for (int bk = 0; bk < K; bk += 32) {
    GLDS16(A + aoff0 + bk, Asw0);
    GLDS16(A + aoff1 + bk, Asw1);
    GLDS16(B + boff0 + bk, Bsw0);
    GLDS16(B + boff1 + bk, Bsw1);
    __syncthreads();
    short8_t af[4], bfr[4];
#pragma unroll
    for (int m = 0; m < 4; ++m)
      af[m] = *(const short8_t*)&As[(wm + m * 16 + (lane & 15)) * 32 + (lane >> 4) * 8];
#pragma unroll
    for (int n = 0; n < 4; ++n)
      bfr[n] = *(const short8_t*)&Bs[(wn + n * 16 + (lane & 15)) * 32 + (lane >> 4) * 8];
#pragma unroll
    for (int m = 0; m < 4; ++m)
#pragma unroll
      for (int n = 0; n < 4; ++n)
        acc[m][n] = __builtin_amdgcn_mfma_f32_16x16x32_bf16(af[m], bfr[n], acc[m][n], 0, 0, 0);
    __syncthreads();
  }

#pragma unroll
  for (int m = 0; m < 4; ++m) {
#pragma unroll
    for (int n = 0; n < 4; ++n) {
      int col = bn + wn + n * 16 + (lane & 15);
      if (col < N) {
        int rbase = bm + wm + m * 16 + (lane >> 4) * 4;
#pragma unroll
        for (int i = 0; i < 4; ++i) {
          long idx = (long)(rbase + i) * N + col;
          if (OUT_BF16) ((short*)C)[idx] = f2bf(acc[m][n][i]);
          else          ((float*)C)[idx] = acc[m][n][i];
        }
      }
    }
  }
}

// ---------------- LSTM recurrent scan (persistent, 220 blocks, dataflow) ------
// xout pre-poisoned with bf16-NaN. Producers fire coherent 8B h stores (no
// wait); consumers poll coherent 16B loads until non-poison -- the poll IS the
// operand fetch (1 LLC flight + observe instead of 4 hops). s_sleep backoff
// prevents spin congestion. red[] is double-buffered by t-parity and there is
// only ONE __syncthreads per step, so waves 1-3 poll step t+1 while wave0
// finishes step t's reduce/gates/store.
__global__ __launch_bounds__(256, 1) void lstm_scan(
    const short* __restrict__ whh,   // [7040][1760] bf16
    const short* __restrict__ xg,    // [4096][7040] bf16 = x @ w_ih^T
    const float* __restrict__ bih, const float* __restrict__ bhh,  // [7040]
    short* __restrict__ xout)        // [4096][1760] bf16 (h history = layer output)
{
  __shared__ short Ws[32][WSTRIDE];        // rows: [gate(4)][j(8)], cols 1760.. zero
  __shared__ float red[2][4][2][64][4];    // [t-parity][wave][acc][lane][i]

  const int wg = blockIdx.x, tid = threadIdx.x, lane = tid & 63, wid = tid >> 6;
  const int j0 = wg * 8;

  // load W slice: slice row r -> global row (r>>3)*HDIM + j0 + (r&7); zero-pad cols
  for (int c = tid; c < 32 * 448; c += 256) {    // 448 x s16x4 per row (1792 cols)
    int r = c / 448, cc = (c % 448) * 4;
    s16x4 v = {0, 0, 0, 0};
    if (cc < HDIM) {
      int grow = (r >> 3) * HDIM + j0 + (r & 7);
      v = *(const s16x4*)&whh[(long)grow * HDIM + cc];
    }
    *(s16x4*)&Ws[r][cc] = v;
  }

  const int b = lane & 15;
  const int jrel = (lane >> 4) * 4;        // valid for lane<32
  const bool active = (wid == 0) && (lane < 32) && (b < 8);

  float bI[4], bF[4], bG[4], bO[4];
  float cst[4] = {0.f, 0.f, 0.f, 0.f};
  if (active) {
#pragma unroll
    for (int i = 0; i < 4; ++i) {
      int j = j0 + jrel + i;
      bI[i] = bih[j]            + bhh[j];
      bF[i] = bih[HDIM + j]     + bhh[HDIM + j];
      bG[i] = bih[2 * HDIM + j] + bhh[2 * HDIM + j];
      bO[i] = bih[3 * HDIM + j] + bhh[3 * HDIM + j];
    }
  }

  const int ks0 = wid * 14;                // 56 chunks of 32; chunk 55 is zero rows
  const int bc = (b < 7) ? b : 7;          // clamp pad batches (cols 8..15 discarded)
  const long hlane = (long)(bc * SEQ) * HDIM + (lane >> 4) * 8;
  const int awrow0 = lane & 15, awrow1 = 16 + (lane & 15);
  const int acol = (lane >> 4) * 8;

  __syncthreads();  // Ws ready

  for (int t = 0; t < SEQ; ++t) {
    const int p = t & 1;
    // xg for this step (plain cached loads; independent of h)
    s16x4 xi, xf, xgg, xo;
    if (active) {
      const short* xrow = xg + (long)(b * SEQ + t) * G4;
      xi  = *(const s16x4*)(xrow + j0 + jrel);
      xf  = *(const s16x4*)(xrow + HDIM + j0 + jrel);
      xgg = *(const s16x4*)(xrow + 2 * HDIM + j0 + jrel);
      xo  = *(const s16x4*)(xrow + 3 * HDIM + j0 + jrel);
    }

    f32x4 acc0 = {0.f, 0.f, 0.f, 0.f}, acc1 = {0.f, 0.f, 0.f, 0.f};
    if (t > 0) {
      const short* hb = xout + hlane + (long)(t - 1) * HDIM;
      uint4 hreg[14];
#pragma unroll
      for (int k = 0; k < 14; ++k) {
        if (ks0 + k < 55) hreg[k] = ld16_coh(hb + (ks0 + k) * 32);
        else              hreg[k] = (uint4){0u, 0u, 0u, 0u};
      }
      // poll until every checked dword is non-poison; backoff on miss
      for (;;) {
        asm volatile("s_waitcnt vmcnt(0)" ::: "memory");
        __builtin_amdgcn_sched_barrier(0);
        unsigned bad = 0;
#pragma unroll
        for (int k = 0; k < 14; ++k) {
          if (ks0 + k < 55) {
            bool pz = (hreg[k].x == POIS) | (hreg[k].y == POIS) |
                      (hreg[k].z == POIS) | (hreg[k].w == POIS);
            bad |= pz ? (1u << k) : 0u;
          }
        }
        if (!__any((int)(bad != 0u))) break;
        __builtin_amdgcn_s_sleep(2);
#pragma unroll
        for (int k = 0; k < 14; ++k)
          if ((ks0 + k < 55) && (bad & (1u << k)))
            hreg[k] = ld16_coh(hb + (ks0 + k) * 32);
      }
      __builtin_amdgcn_sched_barrier(0);
#pragma unroll
      for (int k = 0; k < 14; ++k) {
        int kc = (ks0 + k) * 32 + acol;
        short8_t hv = __builtin_bit_cast(short8_t, hreg[k]);
        short8_t a0 = *(const short8_t*)&Ws[awrow0][kc];
        short8_t a1 = *(const short8_t*)&Ws[awrow1][kc];
        acc0 = __builtin_amdgcn_mfma_f32_16x16x32_bf16(a0, hv, acc0, 0, 0, 0);
        acc1 = __builtin_amdgcn_mfma_f32_16x16x32_bf16(a1, hv, acc1, 0, 0, 0);
      }
    }
    *(f32x4*)&red[p][wid][0][lane][0] = acc0;
    *(f32x4*)&red[p][wid][1][lane][0] = acc1;
    __syncthreads();   // the ONLY per-step sync; parity protects red reuse

    if (wid == 0) {
#pragma unroll
      for (int w = 1; w < 4; ++w) {
        acc0 += *(const f32x4*)&red[p][w][0][lane][0];
        acc1 += *(const f32x4*)&red[p][w][1][lane][0];
      }
      f32x4 fac, oac;   // bring f-gate / o-gate partials to lanes<32
#pragma unroll
      for (int i = 0; i < 4; ++i) {
        fac[i] = __shfl_xor(acc0[i], 32);
        oac[i] = __shfl_xor(acc1[i], 32);
      }
      if (active) {
        s16x4 hv;
#pragma unroll
        for (int i = 0; i < 4; ++i) {
          float pi = acc0[i] + bf2f(xi[i])  + bI[i];
          float pf = fac[i]  + bf2f(xf[i])  + bF[i];
          float pg = acc1[i] + bf2f(xgg[i]) + bG[i];
          float po = oac[i]  + bf2f(xo[i])  + bO[i];
          float ig = fsig(pi), fg = fsig(pf), og = fsig(po);
          float gg = ftanh(pg);
          cst[i] = fg * cst[i] + ig * gg;
          hv[i] = f2bf(og * ftanh(cst[i]));
        }
        st8_coh(xout + (long)(b * SEQ + t) * HDIM + j0 + jrel, hv);  // fire & forget
      }
    }
  }
}

// ---------------- LayerNorm over H ----------------
__global__ __launch_bounds__(256) void ln_fwd(
    const short* __restrict__ x, const float* __restrict__ g, const float* __restrict__ bb,
    short* __restrict__ y)
{
  __shared__ float rs[8];
  const int row = blockIdx.x, tid = threadIdx.x;
  const short* xr = x + (long)row * HDIM;
  float s1 = 0.f, s2 = 0.f;
  for (int c = tid; c < HDIM; c += 256) { float f = bf2f(xr[c]); s1 += f; s2 += f * f; }
  for (int off = 32; off; off >>= 1) { s1 += __shfl_xor(s1, off); s2 += __shfl_xor(s2, off); }
  if ((tid & 63) == 0) { rs[(tid >> 6) * 2] = s1; rs[(tid >> 6) * 2 + 1] = s2; }
  __syncthreads();
  s1 = rs[0] + rs[2] + rs[4] + rs[6];
  s2 = rs[1] + rs[3] + rs[5] + rs[7];
  const float mu = s1 / HDIM;
  const float rstd = rsqrtf(s2 / HDIM - mu * mu + 1e-5f);
  for (int c = tid; c < HDIM; c += 256) {
    float f = bf2f(xr[c]);
    y[(long)row * HDIM + c] = f2bf((f - mu) * rstd * g[c] + bb[c]);
  }
}

// ---------------- host orchestration ----------------
extern "C" void kernel_launch(void* const* d_in, const int* in_sizes, int n_in,
                              void* d_out, int out_size, void* d_ws, size_t ws_size,
                              hipStream_t stream) {
  (void)in_sizes; (void)n_in; (void)out_size; (void)ws_size;
  const int*   ids  = (const int*)d_in[0];
  const float* emb  = (const float*)d_in[1];
  const float* wih[3] = {(const float*)d_in[2], (const float*)d_in[6], (const float*)d_in[10]};
  const float* whh[3] = {(const float*)d_in[3], (const float*)d_in[7], (const float*)d_in[11]};
  const float* bih[3] = {(const float*)d_in[4], (const float*)d_in[8], (const float*)d_in[12]};
  const float* bhh[3] = {(const float*)d_in[5], (const float*)d_in[9], (const float*)d_in[13]};
  const float* lng  = (const float*)d_in[14];
  const float* lnb  = (const float*)d_in[15];
  const float* prjw = (const float*)d_in[16];
  float* out = (float*)d_out;

  char* p = (char*)d_ws;
  auto alloc = [&](size_t bytes) { char* r = p; p += (bytes + 255) & ~(size_t)255; return r; };
  short* emb_b = (short*)alloc((size_t)VPAD * DMODEL * 2);   // 64.4 MB
  short* wbuf  = (short*)alloc((size_t)G4 * HDIM * 2);       // 24.8 MB
  short* xgbuf = (short*)alloc((size_t)MROWS * G4 * 2);      // 57.7 MB
  short* x0    = (short*)alloc((size_t)MROWS * DMODEL * 2);
  short* xb1   = (short*)alloc((size_t)MROWS * HDIM * 2);    // layer0 h (contiguous w/ xb2,xb3)
  short* xb2   = (short*)alloc((size_t)MROWS * HDIM * 2);    // layer1 h
  short* xb3   = (short*)alloc((size_t)MROWS * HDIM * 2);    // layer2 h
  short* pbuf  = (short*)alloc((size_t)MROWS * DMODEL * 2);

  // poison all three h buffers (contiguous): 3*4096*1760 shorts
  {
    long n4 = (long)3 * MROWS * HDIM / 8;   // uint4 count
    fill_poison<<<dim3((unsigned)((n4 + 255) / 256)), dim3(256), 0, stream>>>(
        (unsigned int*)xb1, n4);
  }

  auto cvt = [&](const float* s, short* d, long n) {
    int blocks = (int)((n / 8 + 255) / 256);
    cvt_f32_bf16<<<dim3(blocks), dim3(256), 0, stream>>>(s, d, n);
  };

  cvt(emb, emb_b, (long)VOCAB * DMODEL);
  embed_gather<<<dim3(MROWS), dim3(256), 0, stream>>>(ids, emb, x0);

  short* xin = x0; int kin = DMODEL;
  short* xouts[3] = {xb1, xb2, xb3};
  for (int l = 0; l < 3; ++l) {
    cvt(wih[l], wbuf, (long)G4 * kin);
    gemm_btn<1><<<dim3(G4 / 128, MROWS / 128), dim3(256), 0, stream>>>(
        xin, wbuf, (void*)xgbuf, MROWS, G4, kin);
    cvt(whh[l], wbuf, (long)G4 * HDIM);
    lstm_scan<<<dim3(NWG), dim3(256), 0, stream>>>(
        wbuf, xgbuf, bih[l], bhh[l], xouts[l]);
    xin = xouts[l]; kin = HDIM;
  }

  ln_fwd<<<dim3(MROWS), dim3(256), 0, stream>>>(xb3, lng, lnb, xb2);
  cvt(prjw, wbuf, (long)DMODEL * HDIM);
  gemm_btn<1><<<dim3(DMODEL / 128, MROWS / 128), dim3(256), 0, stream>>>(
      xb2, wbuf, (void*)pbuf, MROWS, DMODEL, HDIM);
  gemm_btn<0><<<dim3((VOCAB + 127) / 128, MROWS / 128), dim3(256), 0, stream>>>(
      pbuf, emb_b, (void*)out, MROWS, VOCAB, DMODEL);
}

// Round 6
// 8881.898 us; speedup vs baseline: 1.4134x; 1.4134x over previous
//
#include <hip/hip_runtime.h>
#include <hip/hip_bf16.h>

#define DMODEL 640
#define HDIM   1760
#define G4     7040      // 4*H
#define VOCAB  50257
#define VPAD   50304     // 393*128
#define SEQ    512
#define MROWS  4096      // B*S
#define NWG    220       // scan workgroups (220*8 = 1760 j's)
#define NCNT   32        // spread arrival counters (one cache line each)
#define WSTRIDE 1800     // Ws row stride in shorts (3600B -> 2-way bank alias = free)
#define POIS   0x7FC07FC0u   // two bf16 NaNs; h = og*tanh(c) in (-1,1) can never encode this

typedef __attribute__((ext_vector_type(8))) short short8_t;
typedef __attribute__((ext_vector_type(4))) short s16x4;
typedef __attribute__((ext_vector_type(4))) float f32x4;

static __device__ __forceinline__ float bf2f(short s) {
  union { unsigned int u; float f; } v;
  v.u = ((unsigned int)(unsigned short)s) << 16;
  return v.f;
}
static __device__ __forceinline__ short f2bf(float f) {
  union { float f; unsigned int u; } v; v.f = f;
  unsigned int r = v.u + 0x7fffu + ((v.u >> 16) & 1u);  // RNE, non-NaN inputs
  return (short)(r >> 16);
}
// fast sigmoid / tanh (v_exp + v_rcp; exact saturation at +-inf)
static __device__ __forceinline__ float fsig(float x) {
  return __builtin_amdgcn_rcpf(1.f + __expf(-x));
}
static __device__ __forceinline__ float ftanh(float x) {
  return 1.f - 2.f * __builtin_amdgcn_rcpf(1.f + __expf(2.f * x));
}

// coherent (bypass L1/L2) ops for cross-XCD h exchange / barrier
static __device__ __forceinline__ uint4 ld16_coh(const short* p) {
  uint4 r;
  asm volatile("global_load_dwordx4 %0, %1, off sc0 sc1" : "=v"(r) : "v"(p));
  return r;
}
static __device__ __forceinline__ int ld4_coh(const int* p) {
  int r;
  asm volatile("global_load_dword %0, %1, off sc0 sc1" : "=v"(r) : "v"(p));
  return r;
}
static __device__ __forceinline__ void st8_coh(short* p, s16x4 v) {
  asm volatile("global_store_dwordx2 %0, %1, off sc0 sc1" :: "v"(p), "v"(v) : "memory");
}

// ---------------- poison fill (data-as-flag init) ----------------
__global__ void fill_poison(unsigned int* __restrict__ dst, long n4) {
  long i = (long)blockIdx.x * blockDim.x + threadIdx.x;
  if (i < n4) {
    uint4 v = {POIS, POIS, POIS, POIS};
    *(uint4*)(dst + i * 4) = v;
  }
}

// ---------------- f32 -> bf16 conversion ----------------
__global__ void cvt_f32_bf16(const float* __restrict__ src, short* __restrict__ dst, long n) {
  long i = ((long)blockIdx.x * blockDim.x + threadIdx.x) * 8;
  if (i + 8 <= n) {
    float4 a = *(const float4*)(src + i);
    float4 b = *(const float4*)(src + i + 4);
    short8_t o;
    o[0] = f2bf(a.x); o[1] = f2bf(a.y); o[2] = f2bf(a.z); o[3] = f2bf(a.w);
    o[4] = f2bf(b.x); o[5] = f2bf(b.y); o[6] = f2bf(b.z); o[7] = f2bf(b.w);
    *(short8_t*)(dst + i) = o;
  } else {
    for (; i < n; ++i) dst[i] = f2bf(src[i]);
  }
}

// ---------------- embedding gather ----------------
__global__ void embed_gather(const int* __restrict__ ids, const float* __restrict__ emb,
                             short* __restrict__ x0) {
  int row = blockIdx.x;            // b*512+s
  int id  = ids[row];
  const float* s = emb + (long)id * DMODEL;
  short* d = x0 + (long)row * DMODEL;
  for (int c = threadIdx.x; c < DMODEL; c += blockDim.x) d[c] = f2bf(s[c]);
}

// ---------------- bf16 MFMA GEMM: C[M,N] = A[M,K] * B[N,K]^T ----------------
#define GLDS16(gp, lp) __builtin_amdgcn_global_load_lds( \
    (const __attribute__((address_space(1))) unsigned int*)(gp), \
    (__attribute__((address_space(3))) unsigned int*)(lp), 16, 0, 0)

template<int OUT_BF16>
__global__ __launch_bounds__(256, 2) void gemm_btn(
    const short* __restrict__ A, const short* __restrict__ B, void* __restrict__ C,
    int M, int N, int K)
{
  __shared__ short As[128 * 32];
  __shared__ short Bs[128 * 32];
  const int bn = blockIdx.x * 128, bm = blockIdx.y * 128;
  const int tid = threadIdx.x, lane = tid & 63, wid = tid >> 6;
  const int wm = (wid >> 1) * 64, wn = (wid & 1) * 64;

  f32x4 acc[4][4] = {};

  const int c0 = 2 * wid;
  const int srow = c0 * 16 + (lane >> 2);
  const int scol = (lane & 3) * 8;
  const long aoff0 = (long)(bm + srow) * K + scol;
  const long aoff1 = aoff0 + 16 * (long)K;
  const long boff0 = (long)(bn + srow) * K + scol;
  const long boff1 = boff0 + 16 * (long)K;
  short* Asw0 = As + c0 * 512; short* Asw1 = Asw0 + 512;
  short* Bsw0 = Bs + c0 * 512; short* Bsw1 = Bsw0 + 512;

  for (int bk = 0; bk < K; bk += 32) {
    GLDS16(A + aoff0 + bk, Asw0);
    GLDS16(A + aoff1 + bk, Asw1);
    GLDS16(B + boff0 + bk, Bsw0);
    GLDS16(B + boff1 + bk, Bsw1);
    __syncthreads();
    short8_t af[4], bfr[4];
#pragma unroll
    for (int m = 0; m < 4; ++m)
      af[m] = *(const short8_t*)&As[(wm + m * 16 + (lane & 15)) * 32 + (lane >> 4) * 8];
#pragma unroll
    for (int n = 0; n < 4; ++n)
      bfr[n] = *(const short8_t*)&Bs[(wn + n * 16 + (lane & 15)) * 32 + (lane >> 4) * 8];
#pragma unroll
    for (int m = 0; m < 4; ++m)
#pragma unroll
      for (int n = 0; n < 4; ++n)
        acc[m][n] = __builtin_amdgcn_mfma_f32_16x16x32_bf16(af[m], bfr[n], acc[m][n], 0, 0, 0);
    __syncthreads();
  }

#pragma unroll
  for (int m = 0; m < 4; ++m) {
#pragma unroll
    for (int n = 0; n < 4; ++n) {
      int col = bn + wn + n * 16 + (lane & 15);
      if (col < N) {
        int rbase = bm + wm + m * 16 + (lane >> 4) * 4;
#pragma unroll
        for (int i = 0; i < 4; ++i) {
          long idx = (long)(rbase + i) * N + col;
          if (OUT_BF16) ((short*)C)[idx] = f2bf(acc[m][n][i]);
          else          ((float*)C)[idx] = acc[m][n][i];
        }
      }
    }
  }
}

// ---------------- LSTM recurrent scan (persistent, 220 blocks) ----------------
// Hybrid sync, congestion-minimized:
//   - producers: gates -> fire-and-forget coherent h store -> arrival RMW on
//     one of 32 spread counter lines (NO vmcnt between: counter is only an
//     APPROXIMATE barrier).
//   - consumers: wave0 polls the 32 counters (lane-parallel + butterfly) until
//     sum >= NWG*step; __syncthreads releases the WG; all waves load their h
//     chunks and verify against pre-poisoned bf16-NaN, re-loading the (rare)
//     chunks whose store hadn't landed yet. Data validity comes from the
//     poison check; the counter just keeps poll traffic off until ~ready.
__global__ __launch_bounds__(256, 1) void lstm_scan(
    const short* __restrict__ whh,   // [7040][1760] bf16
    const short* __restrict__ xg,    // [4096][7040] bf16 = x @ w_ih^T
    const float* __restrict__ bih, const float* __restrict__ bhh,  // [7040]
    short* __restrict__ xout,        // [4096][1760] bf16 (h history, pre-poisoned)
    int* __restrict__ sync, int layer)
{
  __shared__ short Ws[32][WSTRIDE];        // rows: [gate(4)][j(8)], cols 1760.. zero
  __shared__ float red[4][2][64][4];       // K-split partial sums

  const int wg = blockIdx.x, tid = threadIdx.x, lane = tid & 63, wid = tid >> 6;
  const int j0 = wg * 8;

  // load W slice: slice row r -> global row (r>>3)*HDIM + j0 + (r&7); zero-pad cols
  for (int c = tid; c < 32 * 448; c += 256) {    // 448 x s16x4 per row (1792 cols)
    int r = c / 448, cc = (c % 448) * 4;
    s16x4 v = {0, 0, 0, 0};
    if (cc < HDIM) {
      int grow = (r >> 3) * HDIM + j0 + (r & 7);
      v = *(const s16x4*)&whh[(long)grow * HDIM + cc];
    }
    *(s16x4*)&Ws[r][cc] = v;
  }

  const int b = lane & 15;
  const int jrel = (lane >> 4) * 4;        // valid for lane<32
  const bool active = (wid == 0) && (lane < 32) && (b < 8);

  float bI[4], bF[4], bG[4], bO[4];
  float cst[4] = {0.f, 0.f, 0.f, 0.f};
  if (active) {
#pragma unroll
    for (int i = 0; i < 4; ++i) {
      int j = j0 + jrel + i;
      bI[i] = bih[j]            + bhh[j];
      bF[i] = bih[HDIM + j]     + bhh[HDIM + j];
      bG[i] = bih[2 * HDIM + j] + bhh[2 * HDIM + j];
      bO[i] = bih[3 * HDIM + j] + bhh[3 * HDIM + j];
    }
  }

  const int ks0 = wid * 14;                // 56 chunks of 32; chunk 55 is zero rows
  const int bc = (b < 7) ? b : 7;          // clamp pad batches (cols 8..15 discarded)
  const long hlane = (long)(bc * SEQ) * HDIM + (lane >> 4) * 8;
  const int awrow0 = lane & 15, awrow1 = 16 + (lane & 15);
  const int acol = (lane >> 4) * 8;

  int* cnts = sync;                        // 32 counters, 128B apart
  const int* mycnt = &cnts[(lane & 31) * 32];

  __syncthreads();  // Ws ready

  for (int t = 0; t < SEQ; ++t) {
    // xg for this step (plain cached loads; independent of h)
    s16x4 xi, xf, xgg, xo;
    if (active) {
      const short* xrow = xg + (long)(b * SEQ + t) * G4;
      xi  = *(const s16x4*)(xrow + j0 + jrel);
      xf  = *(const s16x4*)(xrow + HDIM + j0 + jrel);
      xgg = *(const s16x4*)(xrow + 2 * HDIM + j0 + jrel);
      xo  = *(const s16x4*)(xrow + 3 * HDIM + j0 + jrel);
    }

    f32x4 acc0 = {0.f, 0.f, 0.f, 0.f}, acc1 = {0.f, 0.f, 0.f, 0.f};
    if (t > 0) {
      // approximate barrier: wave0 polls the spread counters
      if (wid == 0) {
        const int target = NWG * (layer * SEQ + t);
        int total;
        do {
          int v = 0;
          if (lane < 32) v = ld4_coh(mycnt);
          asm volatile("s_waitcnt vmcnt(0)" ::: "memory");
          int s = v;
#pragma unroll
          for (int off = 1; off < 32; off <<= 1) s += __shfl_xor(s, off);
          total = s + __shfl_xor(s, 32);   // uniform across all 64 lanes
        } while (total < target);
      }
      __syncthreads();                     // release waves 1-3

      const short* hb = xout + hlane + (long)(t - 1) * HDIM;
      uint4 hreg[14];
#pragma unroll
      for (int k = 0; k < 14; ++k) {
        if (ks0 + k < 55) hreg[k] = ld16_coh(hb + (ks0 + k) * 32);
        else              hreg[k] = (uint4){0u, 0u, 0u, 0u};
      }
      // verify (counter may lead the data stores): re-load rare poison chunks
      for (;;) {
        asm volatile("s_waitcnt vmcnt(0)" ::: "memory");
        __builtin_amdgcn_sched_barrier(0);
        unsigned bad = 0;
#pragma unroll
        for (int k = 0; k < 14; ++k) {
          if (ks0 + k < 55) {
            bool pz = (hreg[k].x == POIS) | (hreg[k].y == POIS) |
                      (hreg[k].z == POIS) | (hreg[k].w == POIS);
            bad |= pz ? (1u << k) : 0u;
          }
        }
        if (!__any((int)(bad != 0u))) break;
        __builtin_amdgcn_s_sleep(1);
#pragma unroll
        for (int k = 0; k < 14; ++k)
          if ((ks0 + k < 55) && (bad & (1u << k)))
            hreg[k] = ld16_coh(hb + (ks0 + k) * 32);
      }
      __builtin_amdgcn_sched_barrier(0);
      // dual-accumulator MFMA chains (halve dependency depth)
      f32x4 a0b = {0.f, 0.f, 0.f, 0.f}, a1b = {0.f, 0.f, 0.f, 0.f};
#pragma unroll
      for (int k = 0; k < 14; k += 2) {
        int kc0 = (ks0 + k) * 32 + acol;
        int kc1 = (ks0 + k + 1) * 32 + acol;
        short8_t hv0 = __builtin_bit_cast(short8_t, hreg[k]);
        short8_t hv1 = __builtin_bit_cast(short8_t, hreg[k + 1]);
        acc0 = __builtin_amdgcn_mfma_f32_16x16x32_bf16(
            *(const short8_t*)&Ws[awrow0][kc0], hv0, acc0, 0, 0, 0);
        acc1 = __builtin_amdgcn_mfma_f32_16x16x32_bf16(
            *(const short8_t*)&Ws[awrow1][kc0], hv0, acc1, 0, 0, 0);
        a0b  = __builtin_amdgcn_mfma_f32_16x16x32_bf16(
            *(const short8_t*)&Ws[awrow0][kc1], hv1, a0b, 0, 0, 0);
        a1b  = __builtin_amdgcn_mfma_f32_16x16x32_bf16(
            *(const short8_t*)&Ws[awrow1][kc1], hv1, a1b, 0, 0, 0);
      }
      acc0 += a0b; acc1 += a1b;
    }
    *(f32x4*)&red[wid][0][lane][0] = acc0;
    *(f32x4*)&red[wid][1][lane][0] = acc1;
    __syncthreads();

    if (wid == 0) {
#pragma unroll
      for (int w = 1; w < 4; ++w) {
        acc0 += *(const f32x4*)&red[w][0][lane][0];
        acc1 += *(const f32x4*)&red[w][1][lane][0];
      }
      f32x4 fac, oac;   // bring f-gate / o-gate partials to lanes<32
#pragma unroll
      for (int i = 0; i < 4; ++i) {
        fac[i] = __shfl_xor(acc0[i], 32);
        oac[i] = __shfl_xor(acc1[i], 32);
      }
      if (active) {
        s16x4 hv;
#pragma unroll
        for (int i = 0; i < 4; ++i) {
          float pi = acc0[i] + bf2f(xi[i])  + bI[i];
          float pf = fac[i]  + bf2f(xf[i])  + bF[i];
          float pg = acc1[i] + bf2f(xgg[i]) + bG[i];
          float po = oac[i]  + bf2f(xo[i])  + bO[i];
          float ig = fsig(pi), fg = fsig(pf), og = fsig(po);
          float gg = ftanh(pg);
          cst[i] = fg * cst[i] + ig * gg;
          hv[i] = f2bf(og * ftanh(cst[i]));
        }
        st8_coh(xout + (long)(b * SEQ + t) * HDIM + j0 + jrel, hv);  // fire & forget
      }
      if (lane == 0)   // approximate arrival (no vmcnt; poison check covers data)
        __hip_atomic_fetch_add(&cnts[(wg & (NCNT - 1)) * 32], 1,
                               __ATOMIC_RELAXED, __HIP_MEMORY_SCOPE_AGENT);
    }
    // no trailing sync: next step's post-poll __syncthreads protects red reuse
  }
}

// ---------------- LayerNorm over H ----------------
__global__ __launch_bounds__(256) void ln_fwd(
    const short* __restrict__ x, const float* __restrict__ g, const float* __restrict__ bb,
    short* __restrict__ y)
{
  __shared__ float rs[8];
  const int row = blockIdx.x, tid = threadIdx.x;
  const short* xr = x + (long)row * HDIM;
  float s1 = 0.f, s2 = 0.f;
  for (int c = tid; c < HDIM; c += 256) { float f = bf2f(xr[c]); s1 += f; s2 += f * f; }
  for (int off = 32; off; off >>= 1) { s1 += __shfl_xor(s1, off); s2 += __shfl_xor(s2, off); }
  if ((tid & 63) == 0) { rs[(tid >> 6) * 2] = s1; rs[(tid >> 6) * 2 + 1] = s2; }
  __syncthreads();
  s1 = rs[0] + rs[2] + rs[4] + rs[6];
  s2 = rs[1] + rs[3] + rs[5] + rs[7];
  const float mu = s1 / HDIM;
  const float rstd = rsqrtf(s2 / HDIM - mu * mu + 1e-5f);
  for (int c = tid; c < HDIM; c += 256) {
    float f = bf2f(xr[c]);
    y[(long)row * HDIM + c] = f2bf((f - mu) * rstd * g[c] + bb[c]);
  }
}

// ---------------- host orchestration ----------------
extern "C" void kernel_launch(void* const* d_in, const int* in_sizes, int n_in,
                              void* d_out, int out_size, void* d_ws, size_t ws_size,
                              hipStream_t stream) {
  (void)in_sizes; (void)n_in; (void)out_size; (void)ws_size;
  const int*   ids  = (const int*)d_in[0];
  const float* emb  = (const float*)d_in[1];
  const float* wih[3] = {(const float*)d_in[2], (const float*)d_in[6], (const float*)d_in[10]};
  const float* whh[3] = {(const float*)d_in[3], (const float*)d_in[7], (const float*)d_in[11]};
  const float* bih[3] = {(const float*)d_in[4], (const float*)d_in[8], (const float*)d_in[12]};
  const float* bhh[3] = {(const float*)d_in[5], (const float*)d_in[9], (const float*)d_in[13]};
  const float* lng  = (const float*)d_in[14];
  const float* lnb  = (const float*)d_in[15];
  const float* prjw = (const float*)d_in[16];
  float* out = (float*)d_out;

  char* p = (char*)d_ws;
  auto alloc = [&](size_t bytes) { char* r = p; p += (bytes + 255) & ~(size_t)255; return r; };
  short* emb_b = (short*)alloc((size_t)VPAD * DMODEL * 2);   // 64.4 MB
  short* wbuf  = (short*)alloc((size_t)G4 * HDIM * 2);       // 24.8 MB
  short* xgbuf = (short*)alloc((size_t)MROWS * G4 * 2);      // 57.7 MB
  short* x0    = (short*)alloc((size_t)MROWS * DMODEL * 2);
  short* xb1   = (short*)alloc((size_t)MROWS * HDIM * 2);    // layer0 h (contiguous w/ xb2,xb3)
  short* xb2   = (short*)alloc((size_t)MROWS * HDIM * 2);    // layer1 h
  short* xb3   = (short*)alloc((size_t)MROWS * HDIM * 2);    // layer2 h
  short* pbuf  = (short*)alloc((size_t)MROWS * DMODEL * 2);
  int*   sync  = (int*)alloc(4096);

  hipMemsetAsync(sync, 0, 4096, stream);

  // poison all three h buffers (contiguous): 3*4096*1760 shorts
  {
    long n4 = (long)3 * MROWS * HDIM / 8;   // uint4 count
    fill_poison<<<dim3((unsigned)((n4 + 255) / 256)), dim3(256), 0, stream>>>(
        (unsigned int*)xb1, n4);
  }

  auto cvt = [&](const float* s, short* d, long n) {
    int blocks = (int)((n / 8 + 255) / 256);
    cvt_f32_bf16<<<dim3(blocks), dim3(256), 0, stream>>>(s, d, n);
  };

  cvt(emb, emb_b, (long)VOCAB * DMODEL);
  embed_gather<<<dim3(MROWS), dim3(256), 0, stream>>>(ids, emb, x0);

  short* xin = x0; int kin = DMODEL;
  short* xouts[3] = {xb1, xb2, xb3};
  for (int l = 0; l < 3; ++l) {
    cvt(wih[l], wbuf, (long)G4 * kin);
    gemm_btn<1><<<dim3(G4 / 128, MROWS / 128), dim3(256), 0, stream>>>(
        xin, wbuf, (void*)xgbuf, MROWS, G4, kin);
    cvt(whh[l], wbuf, (long)G4 * HDIM);
    lstm_scan<<<dim3(NWG), dim3(256), 0, stream>>>(
        wbuf, xgbuf, bih[l], bhh[l], xouts[l], sync, l);
    xin = xouts[l]; kin = HDIM;
  }

  ln_fwd<<<dim3(MROWS), dim3(256), 0, stream>>>(xb3, lng, lnb, xb2);
  cvt(prjw, wbuf, (long)DMODEL * HDIM);
  gemm_btn<1><<<dim3(DMODEL / 128, MROWS / 128), dim3(256), 0, stream>>>(
      xb2, wbuf, (void*)pbuf, MROWS, DMODEL, HDIM);
  gemm_btn<0><<<dim3((VOCAB + 127) / 128, MROWS / 128), dim3(256), 0, stream>>>(
      pbuf, emb_b, (void*)out, MROWS, VOCAB, DMODEL);
}